// Round 6
// baseline (186.691 us; speedup 1.0000x reference)
//
#include <hip/hip_runtime.h>
#include <hip/hip_bf16.h>

#define N_NODES 4096
#define IN_F 512
#define HEADS 8
#define HPH 8
#define HID 64
#define CLS 16
#define NEG_SLOPE 0.2f
#define MAXD 256   // max neighbors stored per node (Binomial(4096,16/4096): P(>256) ~ 0)
#define KC 128     // K-chunk for proj1 LDS staging

__device__ __forceinline__ float leaky(float x) { return x > 0.f ? x : NEG_SLOPE * x; }

// ---- Kernel 1: adjacency scan -> compact neighbor lists --------------------
// 4096 blocks x 256 threads, tiny LDS (high occupancy). Each thread preloads
// its 4 int4 into registers so 4 loads are always in flight (HBM BW bound).
__global__ __launch_bounds__(256) void scan(const int* __restrict__ adj,
                                            int* __restrict__ deg_g,
                                            int* __restrict__ nbr_g) {
    const int i = blockIdx.x;
    const int t = threadIdx.x;
    __shared__ int nbr[MAXD];
    __shared__ int cnt;
    if (t == 0) cnt = 0;
    __syncthreads();
    const int4* row = (const int4*)(adj + (size_t)i * N_NODES);
    const int4 v0 = row[t], v1 = row[t + 256], v2 = row[t + 512], v3 = row[t + 768];
#define PROC(v, base)                                                            \
    if ((v).x | (v).y | (v).z | (v).w) {                                         \
        if ((v).x) { int p = atomicAdd(&cnt, 1); if (p < MAXD) nbr[p] = (base); }        \
        if ((v).y) { int p = atomicAdd(&cnt, 1); if (p < MAXD) nbr[p] = (base) + 1; }    \
        if ((v).z) { int p = atomicAdd(&cnt, 1); if (p < MAXD) nbr[p] = (base) + 2; }    \
        if ((v).w) { int p = atomicAdd(&cnt, 1); if (p < MAXD) nbr[p] = (base) + 3; }    \
    }
    PROC(v0, 4 * t)
    PROC(v1, 4 * (t + 256))
    PROC(v2, 4 * (t + 512))
    PROC(v3, 4 * (t + 768))
#undef PROC
    __syncthreads();
    const int n = cnt < MAXD ? cnt : MAXD;
    if (t == 0) deg_g[i] = n;
    for (int k = t; k < n; k += 256) nbr_g[(size_t)i * MAXD + k] = nbr[k];
}

// ---- Kernel 2: proj1 g1 = x @ W1 + scores ----------------------------------
// 256 blocks x 64 threads (1 wave). Block = 16 nodes; thread = 4 nodes x 4 cols.
// W1 staged in LDS per K-chunk (block reads W1 once: 512->40 MB L2 traffic).
// All LDS reads are broadcasts or 2-way aliases (free). FMA-issue bound.
__global__ __launch_bounds__(64) void proj1(const float* __restrict__ x,
                                            const float* __restrict__ W1,
                                            const float* __restrict__ a1l,
                                            const float* __restrict__ a1r,
                                            float* __restrict__ g1,
                                            float* __restrict__ sl1,
                                            float* __restrict__ sr1) {
    const int t  = threadIdx.x;          // 0..63
    const int ng = t >> 4;               // node group: nodes ng*4 .. ng*4+3
    const int cg = t & 15;               // col group:  cols  cg*4 .. cg*4+3
    const int i0 = blockIdx.x * 16;
    __shared__ float xs[16][132];        // pitch 132 (mult of 4): rows alias 2-way max
    __shared__ float w1s[KC][68];        // pitch 68 (mult of 4): 2-way alias, free
    float4 a0 = {0,0,0,0}, a1 = {0,0,0,0}, a2 = {0,0,0,0}, a3 = {0,0,0,0};
    for (int kc = 0; kc < IN_F; kc += KC) {
        // stage x tile: 16 rows x KC = 512 float4, 8 per thread (coalesced)
        for (int l = t; l < 16 * KC / 4; l += 64) {
            const int r = l >> 5, c4 = l & 31;      // 32 float4 per row
            *(float4*)&xs[r][c4 * 4] =
                *(const float4*)(x + (size_t)(i0 + r) * IN_F + kc + c4 * 4);
        }
        // stage W1 chunk: KC x 64 = 2048 float4, 32 per thread (coalesced)
        for (int l = t; l < KC * HID / 4; l += 64) {
            const int k = l >> 4, c4 = l & 15;      // 16 float4 per k-row
            *(float4*)&w1s[k][c4 * 4] =
                *(const float4*)(W1 + (size_t)(kc + k) * HID + c4 * 4);
        }
        __syncthreads();
#pragma unroll 4
        for (int k = 0; k < KC; k += 4) {
            const float4 xa = *(const float4*)&xs[ng * 4 + 0][k];
            const float4 xb = *(const float4*)&xs[ng * 4 + 1][k];
            const float4 xc = *(const float4*)&xs[ng * 4 + 2][k];
            const float4 xd = *(const float4*)&xs[ng * 4 + 3][k];
            const float4 w0 = *(const float4*)&w1s[k + 0][cg * 4];
            const float4 w1 = *(const float4*)&w1s[k + 1][cg * 4];
            const float4 w2 = *(const float4*)&w1s[k + 2][cg * 4];
            const float4 w3 = *(const float4*)&w1s[k + 3][cg * 4];
#define ACC(A, xv)                                                       \
            A.x += xv.x * w0.x + xv.y * w1.x + xv.z * w2.x + xv.w * w3.x; \
            A.y += xv.x * w0.y + xv.y * w1.y + xv.z * w2.y + xv.w * w3.y; \
            A.z += xv.x * w0.z + xv.y * w1.z + xv.z * w2.z + xv.w * w3.z; \
            A.w += xv.x * w0.w + xv.y * w1.w + xv.z * w2.w + xv.w * w3.w;
            ACC(a0, xa) ACC(a1, xb) ACC(a2, xc) ACC(a3, xd)
#undef ACC
        }
        __syncthreads();
    }
    // write g1 + head scores. cols cg*4..cg*4+3 all belong to head cg>>1;
    // the head's other 4 cols live in lane t^1 -> one xor-1 shuffle reduces.
    const float4 al = *(const float4*)(a1l + cg * 4);
    const float4 ar = *(const float4*)(a1r + cg * 4);
    const int n0 = i0 + ng * 4;
    const int h = cg >> 1;
    float4 accs[4] = {a0, a1, a2, a3};
#pragma unroll
    for (int j = 0; j < 4; ++j) {
        *(float4*)(g1 + (size_t)(n0 + j) * HID + cg * 4) = accs[j];
        float pl = accs[j].x * al.x + accs[j].y * al.y + accs[j].z * al.z + accs[j].w * al.w;
        float pr = accs[j].x * ar.x + accs[j].y * ar.y + accs[j].z * ar.z + accs[j].w * ar.w;
        pl += __shfl_xor(pl, 1, 64);
        pr += __shfl_xor(pr, 1, 64);
        if ((t & 1) == 0) {
            sl1[(n0 + j) * HEADS + h] = pl;
            sr1[(n0 + j) * HEADS + h] = pr;
        }
    }
}

// ---- Kernel 3: layer-1 attention + ELU + proj2 (fused). One wave per node. -
// No softmax max-pass (|scores| <~ 1.5, exp safe in fp32). Gather x4 unrolled.
__global__ __launch_bounds__(64) void attn1_fused(
        const float* __restrict__ g1,
        const float* __restrict__ sl1,
        const float* __restrict__ sr1,
        const float* __restrict__ W2,
        const float* __restrict__ a2l,
        const float* __restrict__ a2r,
        const int* __restrict__ deg_g,
        const int* __restrict__ nbr_g,
        float* __restrict__ g2,
        float* __restrict__ sl2,
        float* __restrict__ sr2) {
    const int i = blockIdx.x;
    const int t = threadIdx.x;  // c = h*8+d
    __shared__ int nbr[MAXD];
    __shared__ float h1s[HID];
    const int n = deg_g[i];
    for (int k = t; k < n; k += 64) nbr[k] = nbr_g[(size_t)i * MAXD + k];
    __syncthreads();
    const int h = t >> 3;
    const float sl = sl1[i * HEADS + h];
    float denom = 0.f, acc = 0.f;
    int k = 0;
    for (; k + 4 <= n; k += 4) {
        const int j0 = nbr[k], j1 = nbr[k + 1], j2 = nbr[k + 2], j3 = nbr[k + 3];
        const float s0 = sr1[j0 * HEADS + h], s1 = sr1[j1 * HEADS + h];
        const float s2 = sr1[j2 * HEADS + h], s3 = sr1[j3 * HEADS + h];
        const float v0 = g1[(size_t)j0 * HID + t], v1 = g1[(size_t)j1 * HID + t];
        const float v2 = g1[(size_t)j2 * HID + t], v3 = g1[(size_t)j3 * HID + t];
        const float w0 = __expf(leaky(sl + s0)), w1 = __expf(leaky(sl + s1));
        const float w2 = __expf(leaky(sl + s2)), w3 = __expf(leaky(sl + s3));
        denom += (w0 + w1) + (w2 + w3);
        acc += w0 * v0; acc += w1 * v1; acc += w2 * v2; acc += w3 * v3;
    }
    for (; k < n; ++k) {
        const int jj = nbr[k];
        const float w = __expf(leaky(sl + sr1[jj * HEADS + h]));
        denom += w;
        acc += w * g1[(size_t)jj * HID + t];
    }
    float o = (n > 0) ? (acc / denom) : 0.f;
    o = (o > 0.f) ? o : expm1f(o);            // ELU
    h1s[t] = o;
    __syncthreads();
    // proj2: g2[i][c] = sum_k h1s[k] * W2[k][c]; lane t = (quarter q, class c)
    const int q = t >> 4, c = t & 15;
    float p = 0.f;
#pragma unroll
    for (int kk = 0; kk < 16; ++kk) {
        const int k2 = q * 16 + kk;
        p += h1s[k2] * W2[k2 * CLS + c];
    }
    p += __shfl_xor(p, 16, 64);
    p += __shfl_xor(p, 32, 64);
    float pl = 0.f, pr = 0.f;
    if (t < CLS) {
        g2[(size_t)i * CLS + t] = p;
        pl = p * a2l[t];
        pr = p * a2r[t];
    }
#pragma unroll
    for (int off = 1; off < 16; off <<= 1) {
        pl += __shfl_xor(pl, off, 64);
        pr += __shfl_xor(pr, off, 64);
    }
    if (t == 0) { sl2[i] = pl; sr2[i] = pr; }
}

// ---- Kernel 4: layer-2 attention -> fp32 out. 4 nodes/block, x4 unroll. ----
__global__ __launch_bounds__(64) void attn2(
        const int* __restrict__ deg_g,
        const int* __restrict__ nbr_g,
        const float* __restrict__ g2,
        const float* __restrict__ sl2,
        const float* __restrict__ sr2,
        float* __restrict__ out) {
    const int t = threadIdx.x;          // 0..63
    const int g = t >> 4;               // node group 0..3
    const int c = t & 15;               // class
    const int node = blockIdx.x * 4 + g;
    __shared__ int nbrs[4][MAXD];
    const int n = deg_g[node];
    for (int k = c; k < n; k += 16) nbrs[g][k] = nbr_g[(size_t)node * MAXD + k];
    __syncthreads();
    const float sl = sl2[node];
    float denom = 0.f, acc = 0.f;
    int k = 0;
    for (; k + 4 <= n; k += 4) {
        const int j0 = nbrs[g][k], j1 = nbrs[g][k + 1];
        const int j2 = nbrs[g][k + 2], j3 = nbrs[g][k + 3];
        const float s0 = sr2[j0], s1 = sr2[j1], s2 = sr2[j2], s3 = sr2[j3];
        const float v0 = g2[(size_t)j0 * CLS + c], v1 = g2[(size_t)j1 * CLS + c];
        const float v2 = g2[(size_t)j2 * CLS + c], v3 = g2[(size_t)j3 * CLS + c];
        const float w0 = __expf(leaky(sl + s0)), w1 = __expf(leaky(sl + s1));
        const float w2 = __expf(leaky(sl + s2)), w3 = __expf(leaky(sl + s3));
        denom += (w0 + w1) + (w2 + w3);
        acc += w0 * v0; acc += w1 * v1; acc += w2 * v2; acc += w3 * v3;
    }
    for (; k < n; ++k) {
        const int jj = nbrs[g][k];
        const float w = __expf(leaky(sl + sr2[jj]));
        denom += w;
        acc += w * g2[(size_t)jj * CLS + c];
    }
    out[(size_t)node * CLS + c] = (n > 0) ? acc / denom : 0.f;
}

extern "C" void kernel_launch(void* const* d_in, const int* in_sizes, int n_in,
                              void* d_out, int out_size, void* d_ws, size_t ws_size,
                              hipStream_t stream) {
    const float* x   = (const float*)d_in[0];
    const int*   adj = (const int*)d_in[1];
    const float* W1  = (const float*)d_in[2];
    const float* a1l = (const float*)d_in[3];
    const float* a1r = (const float*)d_in[4];
    const float* W2  = (const float*)d_in[5];
    const float* a2l = (const float*)d_in[6];
    const float* a2r = (const float*)d_in[7];
    float* out = (float*)d_out;

    float* ws  = (float*)d_ws;
    float* g1  = ws;                                  // 4096*64
    float* sl1 = g1  + (size_t)N_NODES * HID;         // 4096*8
    float* sr1 = sl1 + (size_t)N_NODES * HEADS;
    float* g2  = sr1 + (size_t)N_NODES * HEADS;       // 4096*16
    float* sl2 = g2  + (size_t)N_NODES * CLS;         // 4096
    float* sr2 = sl2 + N_NODES;
    int*   deg = (int*)(sr2 + N_NODES);               // 4096
    int*   nbr = deg + N_NODES;                       // 4096*MAXD (4 MB)

    scan<<<N_NODES, 256, 0, stream>>>(adj, deg, nbr);
    proj1<<<N_NODES / 16, 64, 0, stream>>>(x, W1, a1l, a1r, g1, sl1, sr1);
    attn1_fused<<<N_NODES, 64, 0, stream>>>(g1, sl1, sr1, W2, a2l, a2r,
                                            deg, nbr, g2, sl2, sr2);
    attn2<<<N_NODES / 4, 64, 0, stream>>>(deg, nbr, g2, sl2, sr2, out);
}

// Round 7
// 138.399 us; speedup vs baseline: 1.3489x; 1.3489x over previous
//
#include <hip/hip_runtime.h>
#include <hip/hip_bf16.h>

#define N_NODES 4096
#define IN_F 512
#define HEADS 8
#define HPH 8
#define HID 64
#define CLS 16
#define NEG_SLOPE 0.2f
#define MAXD 256   // max neighbors stored per node (Binomial(4096,16/4096): P(>256) ~ 0)
#define NT 8       // nodes per proj1 block
#define KH 256     // K-half size (IN_F/2)

__device__ __forceinline__ float leaky(float x) { return x > 0.f ? x : NEG_SLOPE * x; }

// ---- Kernel 1: adjacency scan -> compact neighbor lists --------------------
// 4096 blocks x 256 threads, tiny LDS (high occupancy). Each thread preloads
// its 4 int4 into registers so 4 loads are always in flight (HBM BW bound).
__global__ __launch_bounds__(256) void scan(const int* __restrict__ adj,
                                            int* __restrict__ deg_g,
                                            int* __restrict__ nbr_g) {
    const int i = blockIdx.x;
    const int t = threadIdx.x;
    __shared__ int nbr[MAXD];
    __shared__ int cnt;
    if (t == 0) cnt = 0;
    __syncthreads();
    const int4* row = (const int4*)(adj + (size_t)i * N_NODES);
    const int4 v0 = row[t], v1 = row[t + 256], v2 = row[t + 512], v3 = row[t + 768];
#define PROC(v, base)                                                            \
    if ((v).x | (v).y | (v).z | (v).w) {                                         \
        if ((v).x) { int p = atomicAdd(&cnt, 1); if (p < MAXD) nbr[p] = (base); }        \
        if ((v).y) { int p = atomicAdd(&cnt, 1); if (p < MAXD) nbr[p] = (base) + 1; }    \
        if ((v).z) { int p = atomicAdd(&cnt, 1); if (p < MAXD) nbr[p] = (base) + 2; }    \
        if ((v).w) { int p = atomicAdd(&cnt, 1); if (p < MAXD) nbr[p] = (base) + 3; }    \
    }
    PROC(v0, 4 * t)
    PROC(v1, 4 * (t + 256))
    PROC(v2, 4 * (t + 512))
    PROC(v3, 4 * (t + 768))
#undef PROC
    __syncthreads();
    const int n = cnt < MAXD ? cnt : MAXD;
    if (t == 0) deg_g[i] = n;
    for (int k = t; k < n; k += 256) nbr_g[(size_t)i * MAXD + k] = nbr[k];
}

// ---- Kernel 2: proj1, K-split x2 -------------------------------------------
// grid = (4096/NT) * 2 = 1024 blocks x 128 threads (8 waves/CU).
// block: 8 nodes, one K-half; thread = (node, 4 cols). x staged in LDS,
// W1 float4 straight from L2 (lanes 0..15 cover one contiguous 256B W1 row).
// Partial g1 and partial scores (linear in g) go to disjoint a/b buffers.
__global__ __launch_bounds__(128) void proj1(const float* __restrict__ x,
                                             const float* __restrict__ W1,
                                             const float* __restrict__ a1l,
                                             const float* __restrict__ a1r,
                                             float* __restrict__ g1p,   // [2][N*HID]
                                             float* __restrict__ sl1p,  // [2][N*HEADS]
                                             float* __restrict__ sr1p) {
    const int bx = blockIdx.x;
    const int tile = bx >> 1;
    const int kh = bx & 1;              // K-half
    const int t = threadIdx.x;          // 0..127
    const int nl = t >> 4;              // node 0..7
    const int cg = t & 15;              // col group
    const int i0 = tile * NT;
    __shared__ float xs[NT][KH + 4];    // row pitch 260 floats (16B-aligned, 4-bank skew)
    {   // stage NT x KH floats = 512 float4, 4 per thread, coalesced
        for (int l = t; l < NT * KH / 4; l += 128) {
            const int r = l >> 6, c4 = l & 63;   // 64 float4 per row
            *(float4*)&xs[r][c4 * 4] =
                *(const float4*)(x + (size_t)(i0 + r) * IN_F + kh * KH + c4 * 4);
        }
    }
    __syncthreads();
    float4 acc = make_float4(0.f, 0.f, 0.f, 0.f);
    const float* xrow = &xs[nl][0];
    const float* W1h = W1 + (size_t)kh * KH * HID;
#pragma unroll 4
    for (int k = 0; k < KH; k += 4) {
        const float4 xv = *(const float4*)(xrow + k);
        const float4 w0 = *(const float4*)(W1h + (size_t)(k + 0) * HID + cg * 4);
        const float4 w1 = *(const float4*)(W1h + (size_t)(k + 1) * HID + cg * 4);
        const float4 w2 = *(const float4*)(W1h + (size_t)(k + 2) * HID + cg * 4);
        const float4 w3 = *(const float4*)(W1h + (size_t)(k + 3) * HID + cg * 4);
        acc.x += xv.x * w0.x + xv.y * w1.x + xv.z * w2.x + xv.w * w3.x;
        acc.y += xv.x * w0.y + xv.y * w1.y + xv.z * w2.y + xv.w * w3.y;
        acc.z += xv.x * w0.z + xv.y * w1.z + xv.z * w2.z + xv.w * w3.z;
        acc.w += xv.x * w0.w + xv.y * w1.w + xv.z * w2.w + xv.w * w3.w;
    }
    const int i = i0 + nl;
    float* g1 = g1p + (size_t)kh * N_NODES * HID;
    *(float4*)(g1 + (size_t)i * HID + cg * 4) = acc;
    const float4 al = *(const float4*)(a1l + cg * 4);
    const float4 ar = *(const float4*)(a1r + cg * 4);
    float pl = acc.x * al.x + acc.y * al.y + acc.z * al.z + acc.w * al.w;
    float pr = acc.x * ar.x + acc.y * ar.y + acc.z * ar.z + acc.w * ar.w;
    pl += __shfl_xor(pl, 1, 64);        // lane t^1 = same node, other half of head
    pr += __shfl_xor(pr, 1, 64);
    if ((t & 1) == 0) {
        const int h = cg >> 1;
        sl1p[(size_t)kh * N_NODES * HEADS + i * HEADS + h] = pl;
        sr1p[(size_t)kh * N_NODES * HEADS + i * HEADS + h] = pr;
    }
}

// ---- Kernel 3: layer-1 attention + ELU + proj2 (fused). One wave per node. -
// Sums the two K-half partials at gather time. No softmax max-pass
// (|scores| <~ 1.5, exp safe in fp32). Gather x2 unrolled (8 loads in flight).
__global__ __launch_bounds__(64) void attn1_fused(
        const float* __restrict__ g1p,
        const float* __restrict__ sl1p,
        const float* __restrict__ sr1p,
        const float* __restrict__ W2,
        const float* __restrict__ a2l,
        const float* __restrict__ a2r,
        const int* __restrict__ deg_g,
        const int* __restrict__ nbr_g,
        float* __restrict__ g2,
        float* __restrict__ sl2,
        float* __restrict__ sr2) {
    const int i = blockIdx.x;
    const int t = threadIdx.x;  // c = h*8+d
    __shared__ int nbr[MAXD];
    __shared__ float h1s[HID];
    const float* g1a = g1p;
    const float* g1b = g1p + (size_t)N_NODES * HID;
    const float* sra = sr1p;
    const float* srb = sr1p + (size_t)N_NODES * HEADS;
    const int n = deg_g[i];
    for (int k = t; k < n; k += 64) nbr[k] = nbr_g[(size_t)i * MAXD + k];
    __syncthreads();
    const int h = t >> 3;
    const float sl = sl1p[i * HEADS + h] + sl1p[(size_t)N_NODES * HEADS + i * HEADS + h];
    float denom = 0.f, acc = 0.f;
    int k = 0;
    for (; k + 2 <= n; k += 2) {
        const int j0 = nbr[k], j1 = nbr[k + 1];
        const float s0 = sra[j0 * HEADS + h] + srb[j0 * HEADS + h];
        const float s1 = sra[j1 * HEADS + h] + srb[j1 * HEADS + h];
        const float v0 = g1a[(size_t)j0 * HID + t] + g1b[(size_t)j0 * HID + t];
        const float v1 = g1a[(size_t)j1 * HID + t] + g1b[(size_t)j1 * HID + t];
        const float w0 = __expf(leaky(sl + s0)), w1 = __expf(leaky(sl + s1));
        denom += w0 + w1;
        acc += w0 * v0; acc += w1 * v1;
    }
    for (; k < n; ++k) {
        const int jj = nbr[k];
        const float w = __expf(leaky(sl + sra[jj * HEADS + h] + srb[jj * HEADS + h]));
        denom += w;
        acc += w * (g1a[(size_t)jj * HID + t] + g1b[(size_t)jj * HID + t]);
    }
    float o = (n > 0) ? (acc / denom) : 0.f;
    o = (o > 0.f) ? o : expm1f(o);            // ELU
    h1s[t] = o;
    __syncthreads();
    // proj2: g2[i][c] = sum_k h1s[k] * W2[k][c]; lane t = (quarter q, class c)
    const int q = t >> 4, c = t & 15;
    float p = 0.f;
#pragma unroll
    for (int kk = 0; kk < 16; ++kk) {
        const int k2 = q * 16 + kk;
        p += h1s[k2] * W2[k2 * CLS + c];
    }
    p += __shfl_xor(p, 16, 64);
    p += __shfl_xor(p, 32, 64);
    float pl = 0.f, pr = 0.f;
    if (t < CLS) {
        g2[(size_t)i * CLS + t] = p;
        pl = p * a2l[t];
        pr = p * a2r[t];
    }
#pragma unroll
    for (int off = 1; off < 16; off <<= 1) {
        pl += __shfl_xor(pl, off, 64);
        pr += __shfl_xor(pr, off, 64);
    }
    if (t == 0) { sl2[i] = pl; sr2[i] = pr; }
}

// ---- Kernel 4: layer-2 attention -> fp32 out. 4 nodes/block, x4 unroll. ----
__global__ __launch_bounds__(64) void attn2(
        const int* __restrict__ deg_g,
        const int* __restrict__ nbr_g,
        const float* __restrict__ g2,
        const float* __restrict__ sl2,
        const float* __restrict__ sr2,
        float* __restrict__ out) {
    const int t = threadIdx.x;          // 0..63
    const int g = t >> 4;               // node group 0..3
    const int c = t & 15;               // class
    const int node = blockIdx.x * 4 + g;
    __shared__ int nbrs[4][MAXD];
    const int n = deg_g[node];
    for (int k = c; k < n; k += 16) nbrs[g][k] = nbr_g[(size_t)node * MAXD + k];
    __syncthreads();
    const float sl = sl2[node];
    float denom = 0.f, acc = 0.f;
    int k = 0;
    for (; k + 4 <= n; k += 4) {
        const int j0 = nbrs[g][k], j1 = nbrs[g][k + 1];
        const int j2 = nbrs[g][k + 2], j3 = nbrs[g][k + 3];
        const float s0 = sr2[j0], s1 = sr2[j1], s2 = sr2[j2], s3 = sr2[j3];
        const float v0 = g2[(size_t)j0 * CLS + c], v1 = g2[(size_t)j1 * CLS + c];
        const float v2 = g2[(size_t)j2 * CLS + c], v3 = g2[(size_t)j3 * CLS + c];
        const float w0 = __expf(leaky(sl + s0)), w1 = __expf(leaky(sl + s1));
        const float w2 = __expf(leaky(sl + s2)), w3 = __expf(leaky(sl + s3));
        denom += (w0 + w1) + (w2 + w3);
        acc += w0 * v0; acc += w1 * v1; acc += w2 * v2; acc += w3 * v3;
    }
    for (; k < n; ++k) {
        const int jj = nbrs[g][k];
        const float w = __expf(leaky(sl + sr2[jj]));
        denom += w;
        acc += w * g2[(size_t)jj * CLS + c];
    }
    out[(size_t)node * CLS + c] = (n > 0) ? acc / denom : 0.f;
}

extern "C" void kernel_launch(void* const* d_in, const int* in_sizes, int n_in,
                              void* d_out, int out_size, void* d_ws, size_t ws_size,
                              hipStream_t stream) {
    const float* x   = (const float*)d_in[0];
    const int*   adj = (const int*)d_in[1];
    const float* W1  = (const float*)d_in[2];
    const float* a1l = (const float*)d_in[3];
    const float* a1r = (const float*)d_in[4];
    const float* W2  = (const float*)d_in[5];
    const float* a2l = (const float*)d_in[6];
    const float* a2r = (const float*)d_in[7];
    float* out = (float*)d_out;

    float* ws   = (float*)d_ws;
    float* g1p  = ws;                                   // 2 * 4096*64
    float* sl1p = g1p  + 2 * (size_t)N_NODES * HID;     // 2 * 4096*8
    float* sr1p = sl1p + 2 * (size_t)N_NODES * HEADS;
    float* g2   = sr1p + 2 * (size_t)N_NODES * HEADS;   // 4096*16
    float* sl2  = g2   + (size_t)N_NODES * CLS;         // 4096
    float* sr2  = sl2  + N_NODES;
    int*   deg  = (int*)(sr2 + N_NODES);                // 4096
    int*   nbr  = deg + N_NODES;                        // 4096*MAXD (4 MB)

    scan<<<N_NODES, 256, 0, stream>>>(adj, deg, nbr);
    proj1<<<(N_NODES / NT) * 2, 128, 0, stream>>>(x, W1, a1l, a1r, g1p, sl1p, sr1p);
    attn1_fused<<<N_NODES, 64, 0, stream>>>(g1p, sl1p, sr1p, W2, a2l, a2r,
                                            deg, nbr, g2, sl2, sr2);
    attn2<<<N_NODES / 4, 64, 0, stream>>>(deg, nbr, g2, sl2, sr2, out);
}

// Round 8
// 137.704 us; speedup vs baseline: 1.3557x; 1.0050x over previous
//
#include <hip/hip_runtime.h>
#include <hip/hip_bf16.h>

#define N_NODES 4096
#define IN_F 512
#define HEADS 8
#define HPH 8
#define HID 64
#define CLS 16
#define NEG_SLOPE 0.2f
#define MAXD 256   // max neighbors stored per node (Binomial(4096,16/4096): P(>256) ~ 0)
#define NT 8       // nodes per proj1 block
#define KH 256     // K-half size (IN_F/2)

__device__ __forceinline__ float leaky(float x) { return x > 0.f ? x : NEG_SLOPE * x; }

// ---- Kernel 1: proj1, K-split x2 -------------------------------------------
// grid = (4096/NT) * 2 = 1024 blocks x 128 threads (8 waves/CU).
// block: 8 nodes, one K-half; thread = (node, 4 cols). x staged in LDS,
// W1 float4 straight from L2. Partial g1/scores to disjoint a/b buffers.
__global__ __launch_bounds__(128) void proj1(const float* __restrict__ x,
                                             const float* __restrict__ W1,
                                             const float* __restrict__ a1l,
                                             const float* __restrict__ a1r,
                                             float* __restrict__ g1p,   // [2][N*HID]
                                             float* __restrict__ sl1p,  // [2][N*HEADS]
                                             float* __restrict__ sr1p) {
    const int bx = blockIdx.x;
    const int tile = bx >> 1;
    const int kh = bx & 1;              // K-half
    const int t = threadIdx.x;          // 0..127
    const int nl = t >> 4;              // node 0..7
    const int cg = t & 15;              // col group
    const int i0 = tile * NT;
    __shared__ float xs[NT][KH + 4];
    {   // stage NT x KH floats = 512 float4, 4 per thread, coalesced
        for (int l = t; l < NT * KH / 4; l += 128) {
            const int r = l >> 6, c4 = l & 63;   // 64 float4 per row
            *(float4*)&xs[r][c4 * 4] =
                *(const float4*)(x + (size_t)(i0 + r) * IN_F + kh * KH + c4 * 4);
        }
    }
    __syncthreads();
    float4 acc = make_float4(0.f, 0.f, 0.f, 0.f);
    const float* xrow = &xs[nl][0];
    const float* W1h = W1 + (size_t)kh * KH * HID;
#pragma unroll 4
    for (int k = 0; k < KH; k += 4) {
        const float4 xv = *(const float4*)(xrow + k);
        const float4 w0 = *(const float4*)(W1h + (size_t)(k + 0) * HID + cg * 4);
        const float4 w1 = *(const float4*)(W1h + (size_t)(k + 1) * HID + cg * 4);
        const float4 w2 = *(const float4*)(W1h + (size_t)(k + 2) * HID + cg * 4);
        const float4 w3 = *(const float4*)(W1h + (size_t)(k + 3) * HID + cg * 4);
        acc.x += xv.x * w0.x + xv.y * w1.x + xv.z * w2.x + xv.w * w3.x;
        acc.y += xv.x * w0.y + xv.y * w1.y + xv.z * w2.y + xv.w * w3.y;
        acc.z += xv.x * w0.z + xv.y * w1.z + xv.z * w2.z + xv.w * w3.z;
        acc.w += xv.x * w0.w + xv.y * w1.w + xv.z * w2.w + xv.w * w3.w;
    }
    const int i = i0 + nl;
    float* g1 = g1p + (size_t)kh * N_NODES * HID;
    *(float4*)(g1 + (size_t)i * HID + cg * 4) = acc;
    const float4 al = *(const float4*)(a1l + cg * 4);
    const float4 ar = *(const float4*)(a1r + cg * 4);
    float pl = acc.x * al.x + acc.y * al.y + acc.z * al.z + acc.w * al.w;
    float pr = acc.x * ar.x + acc.y * ar.y + acc.z * ar.z + acc.w * ar.w;
    pl += __shfl_xor(pl, 1, 64);        // lane t^1 = same node, other half of head
    pr += __shfl_xor(pr, 1, 64);
    if ((t & 1) == 0) {
        const int h = cg >> 1;
        sl1p[(size_t)kh * N_NODES * HEADS + i * HEADS + h] = pl;
        sr1p[(size_t)kh * N_NODES * HEADS + i * HEADS + h] = pr;
    }
}

// ---- Kernel 2: adj-row scan + layer-1 attention + ELU + proj2 (all fused) --
// One wave per node. The wave reads its own 16KB adj row (16 int4/lane, fully
// unrolled so all 16 loads are in flight), builds the nbr list in LDS, then
// gathers. Persists nbr lists for attn2. No softmax max-pass (|scores| small).
__global__ __launch_bounds__(64) void attn1_fused(
        const int* __restrict__ adj,
        const float* __restrict__ g1p,
        const float* __restrict__ sl1p,
        const float* __restrict__ sr1p,
        const float* __restrict__ W2,
        const float* __restrict__ a2l,
        const float* __restrict__ a2r,
        float* __restrict__ g2,
        float* __restrict__ sl2,
        float* __restrict__ sr2,
        int* __restrict__ deg_g,
        int* __restrict__ nbr_g) {
    const int i = blockIdx.x;
    const int t = threadIdx.x;  // c = h*8+d
    __shared__ int nbr[MAXD];
    __shared__ float h1s[HID];
    __shared__ int cnt;
    if (t == 0) cnt = 0;
    __syncthreads();
    {   // ---- scan own row: 1024 int4, 16 per lane, all loads issued up front
        const int4* row = (const int4*)(adj + (size_t)i * N_NODES);
        int4 v[16];
#pragma unroll
        for (int s = 0; s < 16; ++s) v[s] = row[t + 64 * s];
#pragma unroll
        for (int s = 0; s < 16; ++s) {
            const int base = 4 * (t + 64 * s);
            if (v[s].x | v[s].y | v[s].z | v[s].w) {
                if (v[s].x) { int p = atomicAdd(&cnt, 1); if (p < MAXD) nbr[p] = base; }
                if (v[s].y) { int p = atomicAdd(&cnt, 1); if (p < MAXD) nbr[p] = base + 1; }
                if (v[s].z) { int p = atomicAdd(&cnt, 1); if (p < MAXD) nbr[p] = base + 2; }
                if (v[s].w) { int p = atomicAdd(&cnt, 1); if (p < MAXD) nbr[p] = base + 3; }
            }
        }
    }
    __syncthreads();
    const int n = cnt < MAXD ? cnt : MAXD;
    if (t == 0) deg_g[i] = n;
    for (int k = t; k < n; k += 64) nbr_g[(size_t)i * MAXD + k] = nbr[k];

    const float* g1a = g1p;
    const float* g1b = g1p + (size_t)N_NODES * HID;
    const float* sra = sr1p;
    const float* srb = sr1p + (size_t)N_NODES * HEADS;
    const int h = t >> 3;
    const float sl = sl1p[i * HEADS + h] + sl1p[(size_t)N_NODES * HEADS + i * HEADS + h];
    float denom = 0.f, acc = 0.f;
    int k = 0;
    for (; k + 2 <= n; k += 2) {
        const int j0 = nbr[k], j1 = nbr[k + 1];
        const float s0 = sra[j0 * HEADS + h] + srb[j0 * HEADS + h];
        const float s1 = sra[j1 * HEADS + h] + srb[j1 * HEADS + h];
        const float v0 = g1a[(size_t)j0 * HID + t] + g1b[(size_t)j0 * HID + t];
        const float v1 = g1a[(size_t)j1 * HID + t] + g1b[(size_t)j1 * HID + t];
        const float w0 = __expf(leaky(sl + s0)), w1 = __expf(leaky(sl + s1));
        denom += w0 + w1;
        acc += w0 * v0; acc += w1 * v1;
    }
    for (; k < n; ++k) {
        const int jj = nbr[k];
        const float w = __expf(leaky(sl + sra[jj * HEADS + h] + srb[jj * HEADS + h]));
        denom += w;
        acc += w * (g1a[(size_t)jj * HID + t] + g1b[(size_t)jj * HID + t]);
    }
    float o = (n > 0) ? (acc / denom) : 0.f;
    o = (o > 0.f) ? o : expm1f(o);            // ELU
    h1s[t] = o;
    __syncthreads();
    // proj2: g2[i][c] = sum_k h1s[k] * W2[k][c]; lane t = (quarter q, class c)
    const int q = t >> 4, c = t & 15;
    float p = 0.f;
#pragma unroll
    for (int kk = 0; kk < 16; ++kk) {
        const int k2 = q * 16 + kk;
        p += h1s[k2] * W2[k2 * CLS + c];
    }
    p += __shfl_xor(p, 16, 64);
    p += __shfl_xor(p, 32, 64);
    float pl = 0.f, pr = 0.f;
    if (t < CLS) {
        g2[(size_t)i * CLS + t] = p;
        pl = p * a2l[t];
        pr = p * a2r[t];
    }
#pragma unroll
    for (int off = 1; off < 16; off <<= 1) {
        pl += __shfl_xor(pl, off, 64);
        pr += __shfl_xor(pr, off, 64);
    }
    if (t == 0) { sl2[i] = pl; sr2[i] = pr; }
}

// ---- Kernel 3: layer-2 attention -> fp32 out. 4 nodes/block, x4 unroll. ----
__global__ __launch_bounds__(64) void attn2(
        const int* __restrict__ deg_g,
        const int* __restrict__ nbr_g,
        const float* __restrict__ g2,
        const float* __restrict__ sl2,
        const float* __restrict__ sr2,
        float* __restrict__ out) {
    const int t = threadIdx.x;          // 0..63
    const int g = t >> 4;               // node group 0..3
    const int c = t & 15;               // class
    const int node = blockIdx.x * 4 + g;
    __shared__ int nbrs[4][MAXD];
    const int n = deg_g[node];
    for (int k = c; k < n; k += 16) nbrs[g][k] = nbr_g[(size_t)node * MAXD + k];
    __syncthreads();
    const float sl = sl2[node];
    float denom = 0.f, acc = 0.f;
    int k = 0;
    for (; k + 4 <= n; k += 4) {
        const int j0 = nbrs[g][k], j1 = nbrs[g][k + 1];
        const int j2 = nbrs[g][k + 2], j3 = nbrs[g][k + 3];
        const float s0 = sr2[j0], s1 = sr2[j1], s2 = sr2[j2], s3 = sr2[j3];
        const float v0 = g2[(size_t)j0 * CLS + c], v1 = g2[(size_t)j1 * CLS + c];
        const float v2 = g2[(size_t)j2 * CLS + c], v3 = g2[(size_t)j3 * CLS + c];
        const float w0 = __expf(leaky(sl + s0)), w1 = __expf(leaky(sl + s1));
        const float w2 = __expf(leaky(sl + s2)), w3 = __expf(leaky(sl + s3));
        denom += (w0 + w1) + (w2 + w3);
        acc += w0 * v0; acc += w1 * v1; acc += w2 * v2; acc += w3 * v3;
    }
    for (; k < n; ++k) {
        const int jj = nbrs[g][k];
        const float w = __expf(leaky(sl + sr2[jj]));
        denom += w;
        acc += w * g2[(size_t)jj * CLS + c];
    }
    out[(size_t)node * CLS + c] = (n > 0) ? acc / denom : 0.f;
}

extern "C" void kernel_launch(void* const* d_in, const int* in_sizes, int n_in,
                              void* d_out, int out_size, void* d_ws, size_t ws_size,
                              hipStream_t stream) {
    const float* x   = (const float*)d_in[0];
    const int*   adj = (const int*)d_in[1];
    const float* W1  = (const float*)d_in[2];
    const float* a1l = (const float*)d_in[3];
    const float* a1r = (const float*)d_in[4];
    const float* W2  = (const float*)d_in[5];
    const float* a2l = (const float*)d_in[6];
    const float* a2r = (const float*)d_in[7];
    float* out = (float*)d_out;

    float* ws   = (float*)d_ws;
    float* g1p  = ws;                                   // 2 * 4096*64
    float* sl1p = g1p  + 2 * (size_t)N_NODES * HID;     // 2 * 4096*8
    float* sr1p = sl1p + 2 * (size_t)N_NODES * HEADS;
    float* g2   = sr1p + 2 * (size_t)N_NODES * HEADS;   // 4096*16
    float* sl2  = g2   + (size_t)N_NODES * CLS;         // 4096
    float* sr2  = sl2  + N_NODES;
    int*   deg  = (int*)(sr2 + N_NODES);                // 4096
    int*   nbr  = deg + N_NODES;                        // 4096*MAXD (4 MB)

    proj1<<<(N_NODES / NT) * 2, 128, 0, stream>>>(x, W1, a1l, a1r, g1p, sl1p, sr1p);
    attn1_fused<<<N_NODES, 64, 0, stream>>>(adj, g1p, sl1p, sr1p, W2, a2l, a2r,
                                            g2, sl2, sr2, deg, nbr);
    attn2<<<N_NODES / 4, 64, 0, stream>>>(deg, nbr, g2, sl2, sr2, out);
}

// Round 9
// 137.505 us; speedup vs baseline: 1.3577x; 1.0015x over previous
//
#include <hip/hip_runtime.h>
#include <hip/hip_bf16.h>

#define N_NODES 4096
#define IN_F 512
#define HEADS 8
#define HPH 8
#define HID 64
#define CLS 16
#define NEG_SLOPE 0.2f
#define MAXD 256   // max neighbors stored per node (Binomial(4096,16/4096): P(>256) ~ 0)

__device__ __forceinline__ float leaky(float x) { return x > 0.f ? x : NEG_SLOPE * x; }

// ---- Kernel 1 (heterogeneous): blocks [0,1024) scan 4 adj rows each (wave=row,
// ---- HBM-bound); blocks [1024,2048) do proj1 with in-block K-quarter split
// ---- (VALU/L2-bound). Scan dispatches first; proj compute overlaps the HBM
// ---- stream across co-resident blocks. Both branches share one 8.3KB LDS pool.
__global__ __launch_bounds__(256, 2) void scan_proj1(
        const int* __restrict__ adj,
        const float* __restrict__ x,
        const float* __restrict__ W1,
        const float* __restrict__ a1l,
        const float* __restrict__ a1r,
        float* __restrict__ g1,
        float* __restrict__ sl1,
        float* __restrict__ sr1,
        int* __restrict__ deg_g,
        int* __restrict__ nbr_g) {
    __shared__ float xs[4][516];          // proj staging; scan branch aliases it
    const int b = blockIdx.x;
    const int t = threadIdx.x;            // 0..255
    if (b < N_NODES / 4) {
        // ---------- scan: wave w handles row 4b+w ----------
        int* nbrS = (int*)&xs[0][0];      // [4][MAXD]
        __shared__ int cntS[4];
        const int w = t >> 6, lane = t & 63;
        if (lane == 0) cntS[w] = 0;       // wave-local init; LDS in-order per wave
        const int i = b * 4 + w;
        const int4* row = (const int4*)(adj + (size_t)i * N_NODES);
        int4 v[16];
#pragma unroll
        for (int s = 0; s < 16; ++s) v[s] = row[lane + 64 * s];
#pragma unroll
        for (int s = 0; s < 16; ++s) {
            const int base = 4 * (lane + 64 * s);
            if (v[s].x | v[s].y | v[s].z | v[s].w) {
                if (v[s].x) { int p = atomicAdd(&cntS[w], 1); if (p < MAXD) nbrS[w * MAXD + p] = base; }
                if (v[s].y) { int p = atomicAdd(&cntS[w], 1); if (p < MAXD) nbrS[w * MAXD + p] = base + 1; }
                if (v[s].z) { int p = atomicAdd(&cntS[w], 1); if (p < MAXD) nbrS[w * MAXD + p] = base + 2; }
                if (v[s].w) { int p = atomicAdd(&cntS[w], 1); if (p < MAXD) nbrS[w * MAXD + p] = base + 3; }
            }
        }
        const int n = cntS[w] < MAXD ? cntS[w] : MAXD;   // wave-local, in-order
        if (lane == 0) deg_g[i] = n;
        for (int k = lane; k < n; k += 64) nbr_g[(size_t)i * MAXD + k] = nbrS[w * MAXD + k];
        return;
    }
    // ---------- proj1: 4 nodes/block; thread = (node=wave, kq, colgroup) -----
    const int i0 = (b - N_NODES / 4) * 4;
    const int nl = t >> 6;                // wave = node
    const int inner = t & 63;
    const int kq = inner >> 4;            // K-quarter (0..3)
    const int cg = inner & 15;            // col group (4 cols)
    for (int l = t; l < 512; l += 256) {  // stage 4 x-rows (512 float4)
        const int r = l >> 7, c4 = l & 127;
        *(float4*)&xs[r][c4 * 4] = *(const float4*)(x + (size_t)(i0 + r) * IN_F + c4 * 4);
    }
    __syncthreads();
    float4 acc = make_float4(0.f, 0.f, 0.f, 0.f);
    const float* xrow = &xs[nl][kq * 128];               // LDS broadcast reads
    const float* Wq = W1 + (size_t)(kq * 128) * HID + cg * 4;
#pragma unroll 4
    for (int k = 0; k < 128; k += 4) {
        const float4 xv = *(const float4*)(xrow + k);
        const float4 w0 = *(const float4*)(Wq + (size_t)(k + 0) * HID);
        const float4 w1 = *(const float4*)(Wq + (size_t)(k + 1) * HID);
        const float4 w2 = *(const float4*)(Wq + (size_t)(k + 2) * HID);
        const float4 w3 = *(const float4*)(Wq + (size_t)(k + 3) * HID);
        acc.x += xv.x * w0.x + xv.y * w1.x + xv.z * w2.x + xv.w * w3.x;
        acc.y += xv.x * w0.y + xv.y * w1.y + xv.z * w2.y + xv.w * w3.y;
        acc.z += xv.x * w0.z + xv.y * w1.z + xv.z * w2.z + xv.w * w3.z;
        acc.w += xv.x * w0.w + xv.y * w1.w + xv.z * w2.w + xv.w * w3.w;
    }
    // butterfly-reduce over kq (lane bits 4..5): full g1 in every lane
#pragma unroll
    for (int m = 16; m <= 32; m <<= 1) {
        acc.x += __shfl_xor(acc.x, m, 64);
        acc.y += __shfl_xor(acc.y, m, 64);
        acc.z += __shfl_xor(acc.z, m, 64);
        acc.w += __shfl_xor(acc.w, m, 64);
    }
    if (kq == 0) {                        // lanes 0..15 of each wave
        const int i = i0 + nl;
        *(float4*)(g1 + (size_t)i * HID + cg * 4) = acc;
        const float4 al = *(const float4*)(a1l + cg * 4);
        const float4 ar = *(const float4*)(a1r + cg * 4);
        float pl = acc.x * al.x + acc.y * al.y + acc.z * al.z + acc.w * al.w;
        float pr = acc.x * ar.x + acc.y * ar.y + acc.z * ar.z + acc.w * ar.w;
        pl += __shfl_xor(pl, 1, 64);      // partner lane cg^1 (same head)
        pr += __shfl_xor(pr, 1, 64);
        if ((cg & 1) == 0) {
            sl1[i * HEADS + (cg >> 1)] = pl;
            sr1[i * HEADS + (cg >> 1)] = pr;
        }
    }
}

// ---- Kernel 2: layer-1 attention + ELU + proj2 (fused). One wave per node. -
// Single full g1/sr1 buffers (3 loads/neighbor). x4 unroll => 8 loads in flight.
__global__ __launch_bounds__(64) void attn1_fused(
        const float* __restrict__ g1,
        const float* __restrict__ sl1,
        const float* __restrict__ sr1,
        const float* __restrict__ W2,
        const float* __restrict__ a2l,
        const float* __restrict__ a2r,
        const int* __restrict__ deg_g,
        const int* __restrict__ nbr_g,
        float* __restrict__ g2,
        float* __restrict__ sl2,
        float* __restrict__ sr2) {
    const int i = blockIdx.x;
    const int t = threadIdx.x;  // c = h*8+d
    __shared__ int nbr[MAXD];
    __shared__ float h1s[HID];
    const int n = deg_g[i];
    for (int k = t; k < n; k += 64) nbr[k] = nbr_g[(size_t)i * MAXD + k];
    __syncthreads();
    const int h = t >> 3;
    const float sl = sl1[i * HEADS + h];
    float denom = 0.f, acc = 0.f;
    int k = 0;
    for (; k + 4 <= n; k += 4) {
        const int j0 = nbr[k], j1 = nbr[k + 1], j2 = nbr[k + 2], j3 = nbr[k + 3];
        const float s0 = sr1[j0 * HEADS + h], s1 = sr1[j1 * HEADS + h];
        const float s2 = sr1[j2 * HEADS + h], s3 = sr1[j3 * HEADS + h];
        const float v0 = g1[(size_t)j0 * HID + t], v1 = g1[(size_t)j1 * HID + t];
        const float v2 = g1[(size_t)j2 * HID + t], v3 = g1[(size_t)j3 * HID + t];
        const float w0 = __expf(leaky(sl + s0)), w1 = __expf(leaky(sl + s1));
        const float w2 = __expf(leaky(sl + s2)), w3 = __expf(leaky(sl + s3));
        denom += (w0 + w1) + (w2 + w3);
        acc += w0 * v0; acc += w1 * v1; acc += w2 * v2; acc += w3 * v3;
    }
    for (; k < n; ++k) {
        const int jj = nbr[k];
        const float w = __expf(leaky(sl + sr1[jj * HEADS + h]));
        denom += w;
        acc += w * g1[(size_t)jj * HID + t];
    }
    float o = (n > 0) ? (acc / denom) : 0.f;
    o = (o > 0.f) ? o : expm1f(o);            // ELU
    h1s[t] = o;
    __syncthreads();
    // proj2: g2[i][c] = sum_k h1s[k] * W2[k][c]; lane t = (quarter q, class c)
    const int q = t >> 4, c = t & 15;
    float p = 0.f;
#pragma unroll
    for (int kk = 0; kk < 16; ++kk) {
        const int k2 = q * 16 + kk;
        p += h1s[k2] * W2[k2 * CLS + c];
    }
    p += __shfl_xor(p, 16, 64);
    p += __shfl_xor(p, 32, 64);
    float pl = 0.f, pr = 0.f;
    if (t < CLS) {
        g2[(size_t)i * CLS + t] = p;
        pl = p * a2l[t];
        pr = p * a2r[t];
    }
#pragma unroll
    for (int off = 1; off < 16; off <<= 1) {
        pl += __shfl_xor(pl, off, 64);
        pr += __shfl_xor(pr, off, 64);
    }
    if (t == 0) { sl2[i] = pl; sr2[i] = pr; }
}

// ---- Kernel 3: layer-2 attention -> fp32 out. 4 nodes/block, x4 unroll. ----
__global__ __launch_bounds__(64) void attn2(
        const int* __restrict__ deg_g,
        const int* __restrict__ nbr_g,
        const float* __restrict__ g2,
        const float* __restrict__ sl2,
        const float* __restrict__ sr2,
        float* __restrict__ out) {
    const int t = threadIdx.x;          // 0..63
    const int g = t >> 4;               // node group 0..3
    const int c = t & 15;               // class
    const int node = blockIdx.x * 4 + g;
    __shared__ int nbrs[4][MAXD];
    const int n = deg_g[node];
    for (int k = c; k < n; k += 16) nbrs[g][k] = nbr_g[(size_t)node * MAXD + k];
    __syncthreads();
    const float sl = sl2[node];
    float denom = 0.f, acc = 0.f;
    int k = 0;
    for (; k + 4 <= n; k += 4) {
        const int j0 = nbrs[g][k], j1 = nbrs[g][k + 1];
        const int j2 = nbrs[g][k + 2], j3 = nbrs[g][k + 3];
        const float s0 = sr2[j0], s1 = sr2[j1], s2 = sr2[j2], s3 = sr2[j3];
        const float v0 = g2[(size_t)j0 * CLS + c], v1 = g2[(size_t)j1 * CLS + c];
        const float v2 = g2[(size_t)j2 * CLS + c], v3 = g2[(size_t)j3 * CLS + c];
        const float w0 = __expf(leaky(sl + s0)), w1 = __expf(leaky(sl + s1));
        const float w2 = __expf(leaky(sl + s2)), w3 = __expf(leaky(sl + s3));
        denom += (w0 + w1) + (w2 + w3);
        acc += w0 * v0; acc += w1 * v1; acc += w2 * v2; acc += w3 * v3;
    }
    for (; k < n; ++k) {
        const int jj = nbrs[g][k];
        const float w = __expf(leaky(sl + sr2[jj]));
        denom += w;
        acc += w * g2[(size_t)jj * CLS + c];
    }
    out[(size_t)node * CLS + c] = (n > 0) ? acc / denom : 0.f;
}

extern "C" void kernel_launch(void* const* d_in, const int* in_sizes, int n_in,
                              void* d_out, int out_size, void* d_ws, size_t ws_size,
                              hipStream_t stream) {
    const float* x   = (const float*)d_in[0];
    const int*   adj = (const int*)d_in[1];
    const float* W1  = (const float*)d_in[2];
    const float* a1l = (const float*)d_in[3];
    const float* a1r = (const float*)d_in[4];
    const float* W2  = (const float*)d_in[5];
    const float* a2l = (const float*)d_in[6];
    const float* a2r = (const float*)d_in[7];
    float* out = (float*)d_out;

    float* ws  = (float*)d_ws;
    float* g1  = ws;                                  // 4096*64
    float* sl1 = g1  + (size_t)N_NODES * HID;         // 4096*8
    float* sr1 = sl1 + (size_t)N_NODES * HEADS;
    float* g2  = sr1 + (size_t)N_NODES * HEADS;       // 4096*16
    float* sl2 = g2  + (size_t)N_NODES * CLS;         // 4096
    float* sr2 = sl2 + N_NODES;
    int*   deg = (int*)(sr2 + N_NODES);               // 4096
    int*   nbr = deg + N_NODES;                       // 4096*MAXD (4 MB)

    scan_proj1<<<2 * (N_NODES / 4), 256, 0, stream>>>(
        adj, x, W1, a1l, a1r, g1, sl1, sr1, deg, nbr);
    attn1_fused<<<N_NODES, 64, 0, stream>>>(g1, sl1, sr1, W2, a2l, a2r,
                                            deg, nbr, g2, sl2, sr2);
    attn2<<<N_NODES / 4, 64, 0, stream>>>(deg, nbr, g2, sl2, sr2, out);
}